// Round 2
// baseline (7486.702 us; speedup 1.0000x reference)
//
#include <hip/hip_runtime.h>
#include <hip/hip_bf16.h>

// GIN forward, round 2: bf16 node features + fp32 scatter-agg, ~219MB ws
// (round 1 used 322MB and crashed -> suspected d_ws overflow).

constexpr int HDIM = 256;

__device__ __forceinline__ float bflo(unsigned int u) { return __uint_as_float(u << 16); }
__device__ __forceinline__ float bfhi(unsigned int u) { return __uint_as_float(u & 0xffff0000u); }
__device__ __forceinline__ unsigned short f2bf(float f) {
    unsigned int u = __float_as_uint(f);
    return (unsigned short)((u + 0x7fffu + ((u >> 16) & 1u)) >> 16);  // RNE
}

// ---- layer-0 scatter: agg0[dst] += x[src], 11 features (fp32) -------------
__global__ __launch_bounds__(256) void scatter0_kernel(
    const float* __restrict__ x, const int* __restrict__ src,
    const int* __restrict__ dst, float* __restrict__ agg0, int n_edges)
{
    int gid = blockIdx.x * 256 + threadIdx.x;
    int e = gid >> 4, f = gid & 15;
    if (e < n_edges && f < 11)
        atomicAdd(&agg0[(size_t)dst[e] * 11 + f], x[(size_t)src[e] * 11 + f]);
}

// ---- scatter for bf16 256-feature layers: one wave per edge ---------------
__global__ __launch_bounds__(256) void scatter_bf_kernel(
    const unsigned short* __restrict__ h, const int* __restrict__ src,
    const int* __restrict__ dst, float* __restrict__ agg, int n_edges)
{
    int e = blockIdx.x * 4 + (threadIdx.x >> 6);
    if (e >= n_edges) return;
    int lane = threadIdx.x & 63;
    int s = src[e], d = dst[e];
    uint2 raw = *(const uint2*)&h[(size_t)s * HDIM + lane * 4];
    float* o = &agg[(size_t)d * HDIM + lane * 4];
    atomicAdd(o + 0, bflo(raw.x));
    atomicAdd(o + 1, bfhi(raw.x));
    atomicAdd(o + 2, bflo(raw.y));
    atomicAdd(o + 3, bfhi(raw.y));
}

// ---- layer-0 GEMM: y = relu((x+agg0) @ w1 + b1), K=11, out bf16 -----------
__global__ __launch_bounds__(256) void gemm0_kernel(
    const float* __restrict__ x, const float* __restrict__ agg0,
    const float* __restrict__ w1, const float* __restrict__ b1,
    unsigned short* __restrict__ out, int M)
{
    int row = blockIdx.x * 4 + (threadIdx.x >> 6);
    if (row >= M) return;
    int lane = threadIdx.x & 63;
    float xr[11];
#pragma unroll
    for (int k = 0; k < 11; k++)
        xr[k] = x[(size_t)row * 11 + k] + agg0[(size_t)row * 11 + k];
    int n = lane * 4;
    float4 acc = *(const float4*)&b1[n];
#pragma unroll
    for (int k = 0; k < 11; k++) {
        float4 w = *(const float4*)&w1[k * HDIM + n];
        acc.x = fmaf(xr[k], w.x, acc.x);
        acc.y = fmaf(xr[k], w.y, acc.y);
        acc.z = fmaf(xr[k], w.z, acc.z);
        acc.w = fmaf(xr[k], w.w, acc.w);
    }
    uint2 o;
    o.x = (unsigned int)f2bf(fmaxf(acc.x, 0.f)) | ((unsigned int)f2bf(fmaxf(acc.y, 0.f)) << 16);
    o.y = (unsigned int)f2bf(fmaxf(acc.z, 0.f)) | ((unsigned int)f2bf(fmaxf(acc.w, 0.f)) << 16);
    *(uint2*)&out[(size_t)row * HDIM + n] = o;
}

// ---- main GEMM: C = act((A [+A2]) @ B + bias), K=N=256 --------------------
// 128x128 tile, BK=16, 256 threads, 8x8 fp32 accum per thread.
// ABF16: A and C are bf16; else fp32. HASA2: fuse fp32 agg add into A-load.
template<bool ABF16, bool HASA2>
__global__ __launch_bounds__(256) void gemm256_t(
    const void* __restrict__ Ap, const float* __restrict__ A2,
    const float* __restrict__ B, const float* __restrict__ bias,
    void* __restrict__ Cp, int M, int do_relu)
{
    __shared__ float As[16][132];   // transposed: As[k][m]
    __shared__ float Bs[16][132];   // Bs[k][n]
    const int tid = threadIdx.x;
    const int tx = tid & 15, ty = tid >> 4;
    const int m0 = blockIdx.x * 128, n0 = blockIdx.y * 128;
    const int arow = tid >> 1, acs = (tid & 1) * 8;
    int gr = m0 + arow; if (gr >= M) gr = M - 1;
    float acc[8][8] = {};

    for (int kt = 0; kt < HDIM; kt += 16) {
        float f[8];
        if (ABF16) {
            const unsigned short* A = (const unsigned short*)Ap;
            uint4 raw = *(const uint4*)&A[(size_t)gr * HDIM + kt + acs];
            f[0] = bflo(raw.x); f[1] = bfhi(raw.x);
            f[2] = bflo(raw.y); f[3] = bfhi(raw.y);
            f[4] = bflo(raw.z); f[5] = bfhi(raw.z);
            f[6] = bflo(raw.w); f[7] = bfhi(raw.w);
        } else {
            const float* A = (const float*)Ap;
            *(float4*)&f[0] = *(const float4*)&A[(size_t)gr * HDIM + kt + acs];
            *(float4*)&f[4] = *(const float4*)&A[(size_t)gr * HDIM + kt + acs + 4];
        }
        if (HASA2) {
            float4 a = *(const float4*)&A2[(size_t)gr * HDIM + kt + acs];
            float4 b = *(const float4*)&A2[(size_t)gr * HDIM + kt + acs + 4];
            f[0] += a.x; f[1] += a.y; f[2] += a.z; f[3] += a.w;
            f[4] += b.x; f[5] += b.y; f[6] += b.z; f[7] += b.w;
        }
#pragma unroll
        for (int j = 0; j < 8; j++) As[acs + j][arow] = f[j];
#pragma unroll
        for (int i = 0; i < 2; i++) {
            int lid = tid * 2 + i;
            int kr = lid >> 5, ns = (lid & 31) * 4;
            *(float4*)&Bs[kr][ns] =
                *(const float4*)&B[(size_t)(kt + kr) * HDIM + n0 + ns];
        }
        __syncthreads();
#pragma unroll
        for (int kl = 0; kl < 16; kl++) {
            float a[8], b[8];
            *(float4*)&a[0] = *(const float4*)&As[kl][ty * 8];
            *(float4*)&a[4] = *(const float4*)&As[kl][ty * 8 + 4];
            *(float4*)&b[0] = *(const float4*)&Bs[kl][tx * 8];
            *(float4*)&b[4] = *(const float4*)&Bs[kl][tx * 8 + 4];
#pragma unroll
            for (int i = 0; i < 8; i++)
#pragma unroll
                for (int j = 0; j < 8; j++)
                    acc[i][j] = fmaf(a[i], b[j], acc[i][j]);
        }
        __syncthreads();
    }

    float bv[8];
    *(float4*)&bv[0] = *(const float4*)&bias[n0 + tx * 8];
    *(float4*)&bv[4] = *(const float4*)&bias[n0 + tx * 8 + 4];
#pragma unroll
    for (int i = 0; i < 8; i++) {
        int gr2 = m0 + ty * 8 + i;
        if (gr2 >= M) break;
        float o[8];
#pragma unroll
        for (int j = 0; j < 8; j++) {
            float v = acc[i][j] + bv[j];
            o[j] = do_relu ? fmaxf(v, 0.f) : v;
        }
        if (ABF16) {
            uint4 o4;
            o4.x = (unsigned int)f2bf(o[0]) | ((unsigned int)f2bf(o[1]) << 16);
            o4.y = (unsigned int)f2bf(o[2]) | ((unsigned int)f2bf(o[3]) << 16);
            o4.z = (unsigned int)f2bf(o[4]) | ((unsigned int)f2bf(o[5]) << 16);
            o4.w = (unsigned int)f2bf(o[6]) | ((unsigned int)f2bf(o[7]) << 16);
            *(uint4*)&((unsigned short*)Cp)[(size_t)gr2 * HDIM + n0 + tx * 8] = o4;
        } else {
            float* C = (float*)Cp;
            *(float4*)&C[(size_t)gr2 * HDIM + n0 + tx * 8]     = *(float4*)&o[0];
            *(float4*)&C[(size_t)gr2 * HDIM + n0 + tx * 8 + 4] = *(float4*)&o[4];
        }
    }
}

// ---- mean-pool over bf16 h ------------------------------------------------
__global__ __launch_bounds__(256) void pool_kernel(
    const unsigned short* __restrict__ h, const int* __restrict__ batch,
    float* __restrict__ sums, float* __restrict__ cnts, int n)
{
    int node = blockIdx.x * 4 + (threadIdx.x >> 6);
    if (node >= n) return;
    int lane = threadIdx.x & 63;
    int b = batch[node];
    uint2 raw = *(const uint2*)&h[(size_t)node * HDIM + lane * 4];
    float* o = &sums[(size_t)b * HDIM + lane * 4];
    atomicAdd(o + 0, bflo(raw.x));
    atomicAdd(o + 1, bfhi(raw.x));
    atomicAdd(o + 2, bflo(raw.y));
    atomicAdd(o + 3, bfhi(raw.y));
    if (lane == 0) atomicAdd(&cnts[b], 1.0f);
}

__global__ __launch_bounds__(256) void pooldiv_kernel(
    float* __restrict__ sums, const float* __restrict__ cnts, int total)
{
    int i = blockIdx.x * 256 + threadIdx.x;
    if (i < total) sums[i] = sums[i] / fmaxf(cnts[i >> 8], 1.0f);
}

// ---- head second linear: out[g] = hh[g,:] . w2 + b2 -----------------------
__global__ __launch_bounds__(256) void head2_kernel(
    const float* __restrict__ hh, const float* __restrict__ w2,
    const float* __restrict__ b2, float* __restrict__ out, int n_graphs)
{
    int g = blockIdx.x * 4 + (threadIdx.x >> 6);
    int lane = threadIdx.x & 63;
    float p = 0.f;
    if (g < n_graphs) {
        float4 v = *(const float4*)&hh[(size_t)g * HDIM + lane * 4];
        float4 w = *(const float4*)&w2[lane * 4];
        p = v.x * w.x + v.y * w.y + v.z * w.z + v.w * w.w;
    }
#pragma unroll
    for (int off = 32; off > 0; off >>= 1) p += __shfl_down(p, off, 64);
    if (g < n_graphs && lane == 0) out[g] = p + b2[0];
}

extern "C" void kernel_launch(void* const* d_in, const int* in_sizes, int n_in,
                              void* d_out, int out_size, void* d_ws, size_t ws_size,
                              hipStream_t stream)
{
    const float* x    = (const float*)d_in[0];
    const int*   ei   = (const int*)d_in[1];
    const int*   batch= (const int*)d_in[2];
    const float* g0w1 = (const float*)d_in[3];
    const float* g0b1 = (const float*)d_in[4];
    const float* g0w2 = (const float*)d_in[5];
    const float* g0b2 = (const float*)d_in[6];
    const float* gw1  = (const float*)d_in[7];
    const float* gb1  = (const float*)d_in[8];
    const float* gw2  = (const float*)d_in[9];
    const float* gb2  = (const float*)d_in[10];
    const float* hw1  = (const float*)d_in[11];
    const float* hb1  = (const float*)d_in[12];
    const float* hw2  = (const float*)d_in[13];
    const float* hb2  = (const float*)d_in[14];

    const int n_nodes  = in_sizes[0] / 11;
    const int n_edges  = in_sizes[1] / 2;
    const int n_graphs = out_size;

    const int* srcp = ei;
    const int* dstp = ei + n_edges;

    // workspace carve-up: two NF-float slabs + small buffers (~219.5 MB)
    const size_t NF = (size_t)n_nodes * HDIM;
    const size_t need_floats = 2 * NF + (size_t)n_nodes * 11
                             + (size_t)n_graphs * HDIM + n_graphs
                             + (size_t)n_graphs * HDIM;
    if (ws_size < need_floats * sizeof(float)) return;  // diagnostic: fail cleanly, don't fault

    float* S0   = (float*)d_ws;       // NF fp32 (agg) / halves hold bf16 h
    float* S1   = S0 + NF;            // NF fp32
    float* agg0 = S1 + NF;
    float* sums = agg0 + (size_t)n_nodes * 11;
    float* cnts = sums + (size_t)n_graphs * HDIM;
    float* hh   = cnts + n_graphs;

    // bf16 views of slab halves (NF bf16 = half a slab's bytes)
    unsigned short* S0lo = (unsigned short*)S0;
    unsigned short* S0hi = (unsigned short*)S0 + NF;
    unsigned short* S1lo = (unsigned short*)S1;
    unsigned short* S1hi = (unsigned short*)S1 + NF;

    const int gemmGridX = (n_nodes + 127) / 128;

    // ---- gin0 (IN=11) ----
    hipMemsetAsync(agg0, 0, (size_t)n_nodes * 11 * sizeof(float), stream);
    scatter0_kernel<<<((size_t)n_edges * 16 + 255) / 256, 256, 0, stream>>>(
        x, srcp, dstp, agg0, n_edges);
    gemm0_kernel<<<(n_nodes + 3) / 4, 256, 0, stream>>>(
        x, agg0, g0w1, g0b1, S0hi, n_nodes);
    gemm256_t<true, false><<<dim3(gemmGridX, 2), 256, 0, stream>>>(
        S0hi, nullptr, g0w2, g0b2, S0lo, n_nodes, 1);

    // ---- 4 GIN layers; parity-scheduled slab reuse ----
    for (int l = 0; l < 4; l++) {
        const float* w1 = gw1 + (size_t)l * HDIM * HDIM;
        const float* b1 = gb1 + (size_t)l * HDIM;
        const float* w2 = gw2 + (size_t)l * HDIM * HDIM;
        const float* b2 = gb2 + (size_t)l * HDIM;
        if ((l & 1) == 0) {  // cur=S0lo, agg=S1(full), y=S0hi, out=S1lo
            hipMemsetAsync(S1, 0, NF * sizeof(float), stream);
            scatter_bf_kernel<<<(n_edges + 3) / 4, 256, 0, stream>>>(
                S0lo, srcp, dstp, S1, n_edges);
            gemm256_t<true, true><<<dim3(gemmGridX, 2), 256, 0, stream>>>(
                S0lo, S1, w1, b1, S0hi, n_nodes, 1);
            gemm256_t<true, false><<<dim3(gemmGridX, 2), 256, 0, stream>>>(
                S0hi, nullptr, w2, b2, S1lo, n_nodes, 1);
        } else {             // cur=S1lo, agg=S0(full), y=S1hi, out=S0lo
            hipMemsetAsync(S0, 0, NF * sizeof(float), stream);
            scatter_bf_kernel<<<(n_edges + 3) / 4, 256, 0, stream>>>(
                S1lo, srcp, dstp, S0, n_edges);
            gemm256_t<true, true><<<dim3(gemmGridX, 2), 256, 0, stream>>>(
                S1lo, S0, w1, b1, S1hi, n_nodes, 1);
            gemm256_t<true, false><<<dim3(gemmGridX, 2), 256, 0, stream>>>(
                S1hi, nullptr, w2, b2, S0lo, n_nodes, 1);
        }
    }
    // final h (bf16) = S0lo (after l=3, odd)

    // ---- mean pool ----
    hipMemsetAsync(sums, 0, (size_t)n_graphs * HDIM * sizeof(float), stream);
    hipMemsetAsync(cnts, 0, (size_t)n_graphs * sizeof(float), stream);
    pool_kernel<<<(n_nodes + 3) / 4, 256, 0, stream>>>(S0lo, batch, sums, cnts, n_nodes);
    pooldiv_kernel<<<((size_t)n_graphs * HDIM + 255) / 256, 256, 0, stream>>>(
        sums, cnts, n_graphs * HDIM);

    // ---- head ----
    gemm256_t<false, false><<<dim3((n_graphs + 127) / 128, 2), 256, 0, stream>>>(
        sums, nullptr, hw1, hb1, hh, n_graphs, 0);
    head2_kernel<<<(n_graphs + 3) / 4, 256, 0, stream>>>(
        hh, hw2, hb2, (float*)d_out, n_graphs);
}

// Round 3
// 1989.644 us; speedup vs baseline: 3.7628x; 3.7628x over previous
//
#include <hip/hip_runtime.h>
#include <hip/hip_bf16.h>

// GIN forward, round 3: atomics-free aggregation via on-device CSR build,
// atomics-free pooling via sorted-batch boundaries. GEMMs unchanged (fp32
// vector ALU) -- MFMA conversion planned next round.

constexpr int HDIM = 256;

__device__ __forceinline__ float bflo(unsigned int u) { return __uint_as_float(u << 16); }
__device__ __forceinline__ float bfhi(unsigned int u) { return __uint_as_float(u & 0xffff0000u); }
__device__ __forceinline__ unsigned short f2bf(float f) {
    unsigned int u = __float_as_uint(f);
    return (unsigned short)((u + 0x7fffu + ((u >> 16) & 1u)) >> 16);  // RNE
}

// ================= CSR build =================
__global__ __launch_bounds__(256) void hist_kernel(
    const int* __restrict__ dst, int* __restrict__ deg, int n_edges)
{
    int e = blockIdx.x * 256 + threadIdx.x;
    if (e < n_edges) atomicAdd(&deg[dst[e]], 1);
}

// block-level exclusive scan; partials[b] = block sum
__global__ __launch_bounds__(256) void scan1_kernel(
    const int* __restrict__ deg, int* __restrict__ scanex,
    int* __restrict__ partials, int n)
{
    __shared__ int s[256];
    int i = blockIdx.x * 256 + threadIdx.x;
    int v = (i < n) ? deg[i] : 0;
    s[threadIdx.x] = v;
    __syncthreads();
#pragma unroll
    for (int off = 1; off < 256; off <<= 1) {
        int t = (threadIdx.x >= off) ? s[threadIdx.x - off] : 0;
        __syncthreads();
        s[threadIdx.x] += t;
        __syncthreads();
    }
    if (i < n) scanex[i] = s[threadIdx.x] - v;
    if (threadIdx.x == 255) partials[blockIdx.x] = s[255];
}

// single-block exclusive scan of up to 512 partials
__global__ __launch_bounds__(512) void scan2_kernel(int* __restrict__ partials, int nb)
{
    __shared__ int s[512];
    int v = (threadIdx.x < nb) ? partials[threadIdx.x] : 0;
    s[threadIdx.x] = v;
    __syncthreads();
#pragma unroll
    for (int off = 1; off < 512; off <<= 1) {
        int t = (threadIdx.x >= off) ? s[threadIdx.x - off] : 0;
        __syncthreads();
        s[threadIdx.x] += t;
        __syncthreads();
    }
    if (threadIdx.x < nb) partials[threadIdx.x] = s[threadIdx.x] - v;
}

__global__ __launch_bounds__(256) void scan3_kernel(
    const int* __restrict__ scanex, const int* __restrict__ partials,
    int* __restrict__ rowptr, int* __restrict__ cursor, int n, int n_edges)
{
    int i = blockIdx.x * 256 + threadIdx.x;
    if (i < n) {
        int v = scanex[i] + partials[blockIdx.x];
        rowptr[i] = v;
        cursor[i] = v;
    }
    if (i == 0) rowptr[n] = n_edges;
}

__global__ __launch_bounds__(256) void fill_kernel(
    const int* __restrict__ src, const int* __restrict__ dst,
    int* __restrict__ cursor, int* __restrict__ csr_src, int n_edges)
{
    int e = blockIdx.x * 256 + threadIdx.x;
    if (e >= n_edges) return;
    int slot = atomicAdd(&cursor[dst[e]], 1);
    csr_src[slot] = src[e];
}

// ================= aggregation (gather) =================
// layer-0: xsum[i,f] = x[i,f] + sum_{j->i} x[j,f]   (11 fp32 feats)
__global__ __launch_bounds__(256) void agg0_kernel(
    const float* __restrict__ x, const int* __restrict__ rowptr,
    const int* __restrict__ csr_src, float* __restrict__ xsum, int n)
{
    int gid = blockIdx.x * 256 + threadIdx.x;
    int node = gid >> 4, f = gid & 15;
    if (node >= n || f >= 11) return;
    float acc = x[(size_t)node * 11 + f];
    int beg = rowptr[node], end = rowptr[node + 1];
    for (int e = beg; e < end; e++)
        acc += x[(size_t)csr_src[e] * 11 + f];
    xsum[(size_t)node * 11 + f] = acc;
}

// 256-feat bf16: out[i,:] = h[i,:] + sum_{j->i} h[j,:]; one wave per node
__global__ __launch_bounds__(256) void agg_bf_kernel(
    const unsigned short* __restrict__ h, const int* __restrict__ rowptr,
    const int* __restrict__ csr_src, unsigned short* __restrict__ out, int n)
{
    int node = blockIdx.x * 4 + (threadIdx.x >> 6);
    if (node >= n) return;
    int lane = threadIdx.x & 63;
    uint2 raw = *(const uint2*)&h[(size_t)node * HDIM + lane * 4];
    float a0 = bflo(raw.x), a1 = bfhi(raw.x), a2 = bflo(raw.y), a3 = bfhi(raw.y);
    int beg = rowptr[node], end = rowptr[node + 1];
    for (int e = beg; e < end; e++) {
        int s = csr_src[e];
        uint2 r = *(const uint2*)&h[(size_t)s * HDIM + lane * 4];
        a0 += bflo(r.x); a1 += bfhi(r.x); a2 += bflo(r.y); a3 += bfhi(r.y);
    }
    uint2 o;
    o.x = (unsigned int)f2bf(a0) | ((unsigned int)f2bf(a1) << 16);
    o.y = (unsigned int)f2bf(a2) | ((unsigned int)f2bf(a3) << 16);
    *(uint2*)&out[(size_t)node * HDIM + lane * 4] = o;
}

// ================= GEMMs =================
// layer-0 GEMM: y = relu(xsum @ w1 + b1), K=11, out bf16
__global__ __launch_bounds__(256) void gemm0_kernel(
    const float* __restrict__ xsum, const float* __restrict__ w1,
    const float* __restrict__ b1, unsigned short* __restrict__ out, int M)
{
    int row = blockIdx.x * 4 + (threadIdx.x >> 6);
    if (row >= M) return;
    int lane = threadIdx.x & 63;
    float xr[11];
#pragma unroll
    for (int k = 0; k < 11; k++) xr[k] = xsum[(size_t)row * 11 + k];
    int n = lane * 4;
    float4 acc = *(const float4*)&b1[n];
#pragma unroll
    for (int k = 0; k < 11; k++) {
        float4 w = *(const float4*)&w1[k * HDIM + n];
        acc.x = fmaf(xr[k], w.x, acc.x);
        acc.y = fmaf(xr[k], w.y, acc.y);
        acc.z = fmaf(xr[k], w.z, acc.z);
        acc.w = fmaf(xr[k], w.w, acc.w);
    }
    uint2 o;
    o.x = (unsigned int)f2bf(fmaxf(acc.x, 0.f)) | ((unsigned int)f2bf(fmaxf(acc.y, 0.f)) << 16);
    o.y = (unsigned int)f2bf(fmaxf(acc.z, 0.f)) | ((unsigned int)f2bf(fmaxf(acc.w, 0.f)) << 16);
    *(uint2*)&out[(size_t)row * HDIM + n] = o;
}

// main GEMM: C = act(A @ B + bias), K=N=256. 128x128 tile, BK=16, 8x8/thread.
// ABF16: A and C bf16; else fp32.
template<bool ABF16>
__global__ __launch_bounds__(256) void gemm256_t(
    const void* __restrict__ Ap, const float* __restrict__ B,
    const float* __restrict__ bias, void* __restrict__ Cp, int M, int do_relu)
{
    __shared__ float As[16][132];   // transposed: As[k][m]
    __shared__ float Bs[16][132];   // Bs[k][n]
    const int tid = threadIdx.x;
    const int tx = tid & 15, ty = tid >> 4;
    const int m0 = blockIdx.x * 128, n0 = blockIdx.y * 128;
    const int arow = tid >> 1, acs = (tid & 1) * 8;
    int gr = m0 + arow; if (gr >= M) gr = M - 1;
    float acc[8][8] = {};

    for (int kt = 0; kt < HDIM; kt += 16) {
        float f[8];
        if (ABF16) {
            const unsigned short* A = (const unsigned short*)Ap;
            uint4 raw = *(const uint4*)&A[(size_t)gr * HDIM + kt + acs];
            f[0] = bflo(raw.x); f[1] = bfhi(raw.x);
            f[2] = bflo(raw.y); f[3] = bfhi(raw.y);
            f[4] = bflo(raw.z); f[5] = bfhi(raw.z);
            f[6] = bflo(raw.w); f[7] = bfhi(raw.w);
        } else {
            const float* A = (const float*)Ap;
            *(float4*)&f[0] = *(const float4*)&A[(size_t)gr * HDIM + kt + acs];
            *(float4*)&f[4] = *(const float4*)&A[(size_t)gr * HDIM + kt + acs + 4];
        }
#pragma unroll
        for (int j = 0; j < 8; j++) As[acs + j][arow] = f[j];
#pragma unroll
        for (int i = 0; i < 2; i++) {
            int lid = tid * 2 + i;
            int kr = lid >> 5, ns = (lid & 31) * 4;
            *(float4*)&Bs[kr][ns] =
                *(const float4*)&B[(size_t)(kt + kr) * HDIM + n0 + ns];
        }
        __syncthreads();
#pragma unroll
        for (int kl = 0; kl < 16; kl++) {
            float a[8], b[8];
            *(float4*)&a[0] = *(const float4*)&As[kl][ty * 8];
            *(float4*)&a[4] = *(const float4*)&As[kl][ty * 8 + 4];
            *(float4*)&b[0] = *(const float4*)&Bs[kl][tx * 8];
            *(float4*)&b[4] = *(const float4*)&Bs[kl][tx * 8 + 4];
#pragma unroll
            for (int i = 0; i < 8; i++)
#pragma unroll
                for (int j = 0; j < 8; j++)
                    acc[i][j] = fmaf(a[i], b[j], acc[i][j]);
        }
        __syncthreads();
    }

    float bv[8];
    *(float4*)&bv[0] = *(const float4*)&bias[n0 + tx * 8];
    *(float4*)&bv[4] = *(const float4*)&bias[n0 + tx * 8 + 4];
#pragma unroll
    for (int i = 0; i < 8; i++) {
        int gr2 = m0 + ty * 8 + i;
        if (gr2 >= M) break;
        float o[8];
#pragma unroll
        for (int j = 0; j < 8; j++) {
            float v = acc[i][j] + bv[j];
            o[j] = do_relu ? fmaxf(v, 0.f) : v;
        }
        if (ABF16) {
            uint4 o4;
            o4.x = (unsigned int)f2bf(o[0]) | ((unsigned int)f2bf(o[1]) << 16);
            o4.y = (unsigned int)f2bf(o[2]) | ((unsigned int)f2bf(o[3]) << 16);
            o4.z = (unsigned int)f2bf(o[4]) | ((unsigned int)f2bf(o[5]) << 16);
            o4.w = (unsigned int)f2bf(o[6]) | ((unsigned int)f2bf(o[7]) << 16);
            *(uint4*)&((unsigned short*)Cp)[(size_t)gr2 * HDIM + n0 + tx * 8] = o4;
        } else {
            float* C = (float*)Cp;
            *(float4*)&C[(size_t)gr2 * HDIM + n0 + tx * 8]     = *(float4*)&o[0];
            *(float4*)&C[(size_t)gr2 * HDIM + n0 + tx * 8 + 4] = *(float4*)&o[4];
        }
    }
}

// ================= pooling via sorted-batch boundaries =================
__global__ __launch_bounds__(256) void bounds_kernel(
    const int* __restrict__ batch, int* __restrict__ gstart, int n, int ngraphs)
{
    int i = blockIdx.x * 256 + threadIdx.x;
    if (i >= n) return;
    int b1 = batch[i];
    int b0 = (i == 0) ? -1 : batch[i - 1];
    for (int g = b0 + 1; g <= b1; g++) gstart[g] = i;
    if (i == n - 1)
        for (int g = b1 + 1; g <= ngraphs; g++) gstart[g] = n;
}

// one wave per graph: pooled[g,:] = mean over rows [gstart[g], gstart[g+1])
__global__ __launch_bounds__(256) void pool_kernel(
    const unsigned short* __restrict__ h, const int* __restrict__ gstart,
    float* __restrict__ pooled, int ngraphs)
{
    int g = blockIdx.x * 4 + (threadIdx.x >> 6);
    if (g >= ngraphs) return;
    int lane = threadIdx.x & 63;
    int beg = gstart[g], end = gstart[g + 1];
    float a0 = 0.f, a1 = 0.f, a2 = 0.f, a3 = 0.f;
    for (int i = beg; i < end; i++) {
        uint2 r = *(const uint2*)&h[(size_t)i * HDIM + lane * 4];
        a0 += bflo(r.x); a1 += bfhi(r.x); a2 += bflo(r.y); a3 += bfhi(r.y);
    }
    float inv = 1.0f / fmaxf((float)(end - beg), 1.0f);
    float4 o = { a0 * inv, a1 * inv, a2 * inv, a3 * inv };
    *(float4*)&pooled[(size_t)g * HDIM + lane * 4] = o;
}

// head second linear: out[g] = hh[g,:] . w2 + b2
__global__ __launch_bounds__(256) void head2_kernel(
    const float* __restrict__ hh, const float* __restrict__ w2,
    const float* __restrict__ b2, float* __restrict__ out, int n_graphs)
{
    int g = blockIdx.x * 4 + (threadIdx.x >> 6);
    int lane = threadIdx.x & 63;
    float p = 0.f;
    if (g < n_graphs) {
        float4 v = *(const float4*)&hh[(size_t)g * HDIM + lane * 4];
        float4 w = *(const float4*)&w2[lane * 4];
        p = v.x * w.x + v.y * w.y + v.z * w.z + v.w * w.w;
    }
#pragma unroll
    for (int off = 32; off > 0; off >>= 1) p += __shfl_down(p, off, 64);
    if (g < n_graphs && lane == 0) out[g] = p + b2[0];
}

extern "C" void kernel_launch(void* const* d_in, const int* in_sizes, int n_in,
                              void* d_out, int out_size, void* d_ws, size_t ws_size,
                              hipStream_t stream)
{
    const float* x    = (const float*)d_in[0];
    const int*   ei   = (const int*)d_in[1];
    const int*   batch= (const int*)d_in[2];
    const float* g0w1 = (const float*)d_in[3];
    const float* g0b1 = (const float*)d_in[4];
    const float* g0w2 = (const float*)d_in[5];
    const float* g0b2 = (const float*)d_in[6];
    const float* gw1  = (const float*)d_in[7];
    const float* gb1  = (const float*)d_in[8];
    const float* gw2  = (const float*)d_in[9];
    const float* gb2  = (const float*)d_in[10];
    const float* hw1  = (const float*)d_in[11];
    const float* hb1  = (const float*)d_in[12];
    const float* hw2  = (const float*)d_in[13];
    const float* hb2  = (const float*)d_in[14];

    const int n_nodes  = in_sizes[0] / 11;
    const int n_edges  = in_sizes[1] / 2;
    const int n_graphs = out_size;

    const int* srcp = ei;
    const int* dstp = ei + n_edges;

    // ---- workspace carve-up (bytes) ----
    const size_t NF = (size_t)n_nodes * HDIM;
    char* p = (char*)d_ws;
    unsigned short* H0 = (unsigned short*)p; p += NF * 2;   // 51.2 MB
    unsigned short* H1 = (unsigned short*)p; p += NF * 2;
    unsigned short* H2 = (unsigned short*)p; p += NF * 2;
    float* xsum    = (float*)p; p += (size_t)n_nodes * 11 * 4;
    float* pooled  = (float*)p; p += (size_t)n_graphs * HDIM * 4;
    float* hh      = (float*)p; p += (size_t)n_graphs * HDIM * 4;
    int* deg       = (int*)p; p += (size_t)n_nodes * 4;
    int* scanex    = (int*)p; p += (size_t)n_nodes * 4;
    int* partials  = (int*)p; p += 512 * 4;
    int* rowptr    = (int*)p; p += ((size_t)n_nodes + 1) * 4;
    int* cursor    = (int*)p; p += (size_t)n_nodes * 4;
    int* csr_src   = (int*)p; p += (size_t)n_edges * 4;
    int* gstart    = (int*)p; p += ((size_t)n_graphs + 1) * 4;
    if ((size_t)(p - (char*)d_ws) > ws_size) return;  // fail cleanly, don't fault

    const int nblk = (n_nodes + 255) / 256;  // 391 <= 512, scan2 requirement

    // ---- CSR build ----
    hipMemsetAsync(deg, 0, (size_t)n_nodes * 4, stream);
    hist_kernel<<<(n_edges + 255) / 256, 256, 0, stream>>>(dstp, deg, n_edges);
    scan1_kernel<<<nblk, 256, 0, stream>>>(deg, scanex, partials, n_nodes);
    scan2_kernel<<<1, 512, 0, stream>>>(partials, nblk);
    scan3_kernel<<<nblk, 256, 0, stream>>>(scanex, partials, rowptr, cursor,
                                           n_nodes, n_edges);
    fill_kernel<<<(n_edges + 255) / 256, 256, 0, stream>>>(
        srcp, dstp, cursor, csr_src, n_edges);

    // ---- graph boundaries for pooling ----
    bounds_kernel<<<nblk, 256, 0, stream>>>(batch, gstart, n_nodes, n_graphs);

    const int gemmGridX = (n_nodes + 127) / 128;
    const int aggGrid   = (n_nodes + 3) / 4;

    // ---- gin0 (IN=11) ----
    agg0_kernel<<<((size_t)n_nodes * 16 + 255) / 256, 256, 0, stream>>>(
        x, rowptr, csr_src, xsum, n_nodes);
    gemm0_kernel<<<aggGrid, 256, 0, stream>>>(xsum, g0w1, g0b1, H1, n_nodes);
    gemm256_t<true><<<dim3(gemmGridX, 2), 256, 0, stream>>>(
        H1, g0w2, g0b2, H0, n_nodes, 1);

    // ---- 4 GIN layers: cur -> (agg) t -> (gemm1) y -> (gemm2) out ----
    // buffers rotate: cur=H0, t=H1, y=H2, out=H1 (t dead after gemm1)
    unsigned short* cur = H0;
    unsigned short* t   = H1;
    unsigned short* y   = H2;
    for (int l = 0; l < 4; l++) {
        const float* w1 = gw1 + (size_t)l * HDIM * HDIM;
        const float* b1 = gb1 + (size_t)l * HDIM;
        const float* w2 = gw2 + (size_t)l * HDIM * HDIM;
        const float* b2 = gb2 + (size_t)l * HDIM;
        agg_bf_kernel<<<aggGrid, 256, 0, stream>>>(cur, rowptr, csr_src, t, n_nodes);
        gemm256_t<true><<<dim3(gemmGridX, 2), 256, 0, stream>>>(t, w1, b1, y, n_nodes, 1);
        gemm256_t<true><<<dim3(gemmGridX, 2), 256, 0, stream>>>(y, w2, b2, t, n_nodes, 1);
        // rotate: new cur = t; old cur becomes scratch
        unsigned short* dead = cur;
        cur = t; t = dead;  // y stays scratch
    }

    // ---- mean pool (atomics-free) ----
    pool_kernel<<<(n_graphs + 3) / 4, 256, 0, stream>>>(cur, gstart, pooled, n_graphs);

    // ---- head ----
    gemm256_t<false><<<dim3((n_graphs + 127) / 128, 2), 256, 0, stream>>>(
        pooled, hw1, hb1, hh, n_graphs, 0);
    head2_kernel<<<(n_graphs + 3) / 4, 256, 0, stream>>>(
        hh, hw2, hb2, (float*)d_out, n_graphs);
}

// Round 4
// 789.584 us; speedup vs baseline: 9.4818x; 2.5199x over previous
//
#include <hip/hip_runtime.h>
#include <hip/hip_bf16.h>

// GIN forward, round 4: bf16 MFMA GEMM (16x16x32) for the 9 big 256x256 GEMMs.
// Weights converted+transposed to bf16 on-device each launch (capture-safe).
// Aggregation/pooling unchanged from round 3 (atomics-free CSR gather).

constexpr int HDIM = 256;

typedef short v8s __attribute__((ext_vector_type(8)));
typedef float v4f __attribute__((ext_vector_type(4)));

__device__ __forceinline__ float bflo(unsigned int u) { return __uint_as_float(u << 16); }
__device__ __forceinline__ float bfhi(unsigned int u) { return __uint_as_float(u & 0xffff0000u); }
__device__ __forceinline__ unsigned short f2bf(float f) {
    unsigned int u = __float_as_uint(f);
    return (unsigned short)((u + 0x7fffu + ((u >> 16) & 1u)) >> 16);  // RNE
}

__device__ __forceinline__ void gload16(const void* g, void* l) {
    __builtin_amdgcn_global_load_lds(
        (const __attribute__((address_space(1))) unsigned int*)g,
        (__attribute__((address_space(3))) unsigned int*)l, 16, 0, 0);
}

// ================= CSR build =================
__global__ __launch_bounds__(256) void hist_kernel(
    const int* __restrict__ dst, int* __restrict__ deg, int n_edges)
{
    int e = blockIdx.x * 256 + threadIdx.x;
    if (e < n_edges) atomicAdd(&deg[dst[e]], 1);
}

__global__ __launch_bounds__(256) void scan1_kernel(
    const int* __restrict__ deg, int* __restrict__ scanex,
    int* __restrict__ partials, int n)
{
    __shared__ int s[256];
    int i = blockIdx.x * 256 + threadIdx.x;
    int v = (i < n) ? deg[i] : 0;
    s[threadIdx.x] = v;
    __syncthreads();
#pragma unroll
    for (int off = 1; off < 256; off <<= 1) {
        int t = (threadIdx.x >= off) ? s[threadIdx.x - off] : 0;
        __syncthreads();
        s[threadIdx.x] += t;
        __syncthreads();
    }
    if (i < n) scanex[i] = s[threadIdx.x] - v;
    if (threadIdx.x == 255) partials[blockIdx.x] = s[255];
}

__global__ __launch_bounds__(512) void scan2_kernel(int* __restrict__ partials, int nb)
{
    __shared__ int s[512];
    int v = (threadIdx.x < nb) ? partials[threadIdx.x] : 0;
    s[threadIdx.x] = v;
    __syncthreads();
#pragma unroll
    for (int off = 1; off < 512; off <<= 1) {
        int t = (threadIdx.x >= off) ? s[threadIdx.x - off] : 0;
        __syncthreads();
        s[threadIdx.x] += t;
        __syncthreads();
    }
    if (threadIdx.x < nb) partials[threadIdx.x] = s[threadIdx.x] - v;
}

__global__ __launch_bounds__(256) void scan3_kernel(
    const int* __restrict__ scanex, const int* __restrict__ partials,
    int* __restrict__ rowptr, int* __restrict__ cursor, int n, int n_edges)
{
    int i = blockIdx.x * 256 + threadIdx.x;
    if (i < n) {
        int v = scanex[i] + partials[blockIdx.x];
        rowptr[i] = v;
        cursor[i] = v;
    }
    if (i == 0) rowptr[n] = n_edges;
}

__global__ __launch_bounds__(256) void fill_kernel(
    const int* __restrict__ src, const int* __restrict__ dst,
    int* __restrict__ cursor, int* __restrict__ csr_src, int n_edges)
{
    int e = blockIdx.x * 256 + threadIdx.x;
    if (e >= n_edges) return;
    int slot = atomicAdd(&cursor[dst[e]], 1);
    csr_src[slot] = src[e];
}

// ================= weight convert: Wt[n][k] = bf16(W[k][n]) =================
// 9 matrices: m=0 -> g0w2; m=1..4 -> gw1[m-1]; m=5..8 -> gw2[m-5]
__global__ __launch_bounds__(256) void convw_kernel(
    const float* __restrict__ g0w2, const float* __restrict__ gw1,
    const float* __restrict__ gw2, unsigned short* __restrict__ Bts)
{
    int gid = blockIdx.x * 256 + threadIdx.x;
    if (gid >= 9 * 65536) return;
    int m = gid >> 16;
    int e = gid & 0xffff;
    int n = e >> 8, k = e & 255;
    const float* W = (m == 0) ? g0w2
                   : (m <= 4) ? gw1 + (size_t)(m - 1) * 65536
                              : gw2 + (size_t)(m - 5) * 65536;
    Bts[(size_t)m * 65536 + n * 256 + k] = f2bf(W[k * 256 + n]);
}

// ================= aggregation (gather) =================
__global__ __launch_bounds__(256) void agg0_kernel(
    const float* __restrict__ x, const int* __restrict__ rowptr,
    const int* __restrict__ csr_src, float* __restrict__ xsum, int n)
{
    int gid = blockIdx.x * 256 + threadIdx.x;
    int node = gid >> 4, f = gid & 15;
    if (node >= n || f >= 11) return;
    float acc = x[(size_t)node * 11 + f];
    int beg = rowptr[node], end = rowptr[node + 1];
    for (int e = beg; e < end; e++)
        acc += x[(size_t)csr_src[e] * 11 + f];
    xsum[(size_t)node * 11 + f] = acc;
}

__global__ __launch_bounds__(256) void agg_bf_kernel(
    const unsigned short* __restrict__ h, const int* __restrict__ rowptr,
    const int* __restrict__ csr_src, unsigned short* __restrict__ out, int n)
{
    int node = blockIdx.x * 4 + (threadIdx.x >> 6);
    if (node >= n) return;
    int lane = threadIdx.x & 63;
    uint2 raw = *(const uint2*)&h[(size_t)node * HDIM + lane * 4];
    float a0 = bflo(raw.x), a1 = bfhi(raw.x), a2 = bflo(raw.y), a3 = bfhi(raw.y);
    int beg = rowptr[node], end = rowptr[node + 1];
    for (int e = beg; e < end; e++) {
        int s = csr_src[e];
        uint2 r = *(const uint2*)&h[(size_t)s * HDIM + lane * 4];
        a0 += bflo(r.x); a1 += bfhi(r.x); a2 += bflo(r.y); a3 += bfhi(r.y);
    }
    uint2 o;
    o.x = (unsigned int)f2bf(a0) | ((unsigned int)f2bf(a1) << 16);
    o.y = (unsigned int)f2bf(a2) | ((unsigned int)f2bf(a3) << 16);
    *(uint2*)&out[(size_t)node * HDIM + lane * 4] = o;
}

// ================= layer-0 GEMM (K=11) =================
__global__ __launch_bounds__(256) void gemm0_kernel(
    const float* __restrict__ xsum, const float* __restrict__ w1,
    const float* __restrict__ b1, unsigned short* __restrict__ out, int M)
{
    int row = blockIdx.x * 4 + (threadIdx.x >> 6);
    if (row >= M) return;
    int lane = threadIdx.x & 63;
    float xr[11];
#pragma unroll
    for (int k = 0; k < 11; k++) xr[k] = xsum[(size_t)row * 11 + k];
    int n = lane * 4;
    float4 acc = *(const float4*)&b1[n];
#pragma unroll
    for (int k = 0; k < 11; k++) {
        float4 w = *(const float4*)&w1[k * HDIM + n];
        acc.x = fmaf(xr[k], w.x, acc.x);
        acc.y = fmaf(xr[k], w.y, acc.y);
        acc.z = fmaf(xr[k], w.z, acc.z);
        acc.w = fmaf(xr[k], w.w, acc.w);
    }
    uint2 o;
    o.x = (unsigned int)f2bf(fmaxf(acc.x, 0.f)) | ((unsigned int)f2bf(fmaxf(acc.y, 0.f)) << 16);
    o.y = (unsigned int)f2bf(fmaxf(acc.z, 0.f)) | ((unsigned int)f2bf(fmaxf(acc.w, 0.f)) << 16);
    *(uint2*)&out[(size_t)row * HDIM + n] = o;
}

// ================= MFMA GEMM: C = act(A @ W + bias) =================
// A bf16 [M][256] row-major; Wt bf16 [256][256] with Wt[n][k]=W[k][n];
// C bf16 [M][256]. Tile 128x128, BK=32, 256 threads (4 waves, 64x64 each).
// LDS slot swizzle: slot(row,ko) = row*4 + ((ko + (row>>1)) & 3) keeps
// frag ds_read_b128 bank aliasing <= 2-way (free per m136).
__global__ __launch_bounds__(256) void gemm_mfma(
    const unsigned short* __restrict__ A, const unsigned short* __restrict__ Wt,
    const float* __restrict__ bias, unsigned short* __restrict__ C,
    int M, int do_relu)
{
    __shared__ short lds[2][512 * 8];   // 16 KB: A tile | B tile (512 slots x 16B)
    const int tid = threadIdx.x;
    const int w = tid >> 6, lane = tid & 63;
    const int q = lane >> 4, r = lane & 15;
    const int rh = w & 1, ch = w >> 1;
    const int m0 = blockIdx.x * 128, n0 = blockIdx.y * 128;

    v4f acc[4][4];
#pragma unroll
    for (int i = 0; i < 4; i++)
#pragma unroll
        for (int j = 0; j < 4; j++)
            acc[i][j] = (v4f){0.f, 0.f, 0.f, 0.f};

    for (int kt = 0; kt < HDIM; kt += 32) {
#pragma unroll
        for (int rd = 0; rd < 2; rd++) {
            int cb = rd * 256 + w * 64;          // wave-uniform slot base
            int s  = cb + lane;
            int row = s >> 2;
            int ko  = ((s & 3) - (row >> 1)) & 3; // invert swizzle
            int gr = m0 + row; if (gr >= M) gr = M - 1;
            gload16(&A[(size_t)gr * HDIM + kt + ko * 8],  &lds[0][cb * 8]);
            gload16(&Wt[(size_t)(n0 + row) * HDIM + kt + ko * 8], &lds[1][cb * 8]);
        }
        __syncthreads();   // compiler drains vmcnt before s_barrier
        v8s af[4], bf[4];
#pragma unroll
        for (int mi = 0; mi < 4; mi++) {
            int row = rh * 64 + mi * 16 + r;
            int slot = row * 4 + ((q + (row >> 1)) & 3);
            af[mi] = *(const v8s*)&lds[0][slot * 8];
        }
#pragma unroll
        for (int ni = 0; ni < 4; ni++) {
            int row = ch * 64 + ni * 16 + r;
            int slot = row * 4 + ((q + (row >> 1)) & 3);
            bf[ni] = *(const v8s*)&lds[1][slot * 8];
        }
#pragma unroll
        for (int mi = 0; mi < 4; mi++)
#pragma unroll
            for (int ni = 0; ni < 4; ni++)
                acc[mi][ni] = __builtin_amdgcn_mfma_f32_16x16x32_bf16(
                    af[mi], bf[ni], acc[mi][ni], 0, 0, 0);
        __syncthreads();
    }

    // epilogue: per-wave LDS bounce for coalesced bf16 stores
    float bv[4];
#pragma unroll
    for (int ni = 0; ni < 4; ni++)
        bv[ni] = bias[n0 + ch * 64 + ni * 16 + r];

    short* cw = &lds[0][0] + w * (16 * 72);   // 16 rows x 64 cols, stride 72
#pragma unroll
    for (int mi = 0; mi < 4; mi++) {
#pragma unroll
        for (int ni = 0; ni < 4; ni++)
#pragma unroll
            for (int i = 0; i < 4; i++) {
                float v = acc[mi][ni][i] + bv[ni];
                if (do_relu) v = fmaxf(v, 0.f);
                cw[(q * 4 + i) * 72 + ni * 16 + r] = (short)f2bf(v);
            }
        __syncthreads();
        int row = lane >> 2, seg = lane & 3;
        int gm = m0 + rh * 64 + mi * 16 + row;
        if (gm < M) {
            v8s p0 = *(const v8s*)&cw[row * 72 + seg * 16];
            v8s p1 = *(const v8s*)&cw[row * 72 + seg * 16 + 8];
            size_t o = (size_t)gm * HDIM + n0 + ch * 64 + seg * 16;
            *(v8s*)&C[o]     = p0;
            *(v8s*)&C[o + 8] = p1;
        }
        __syncthreads();
    }
}

// ================= head GEMM (fp32 in/out, M=5000) =================
__global__ __launch_bounds__(256) void gemm_head(
    const float* __restrict__ A, const float* __restrict__ B,
    const float* __restrict__ bias, float* __restrict__ C, int M)
{
    __shared__ float As[16][132];
    __shared__ float Bs[16][132];
    const int tid = threadIdx.x;
    const int tx = tid & 15, ty = tid >> 4;
    const int m0 = blockIdx.x * 128, n0 = blockIdx.y * 128;
    const int arow = tid >> 1, acs = (tid & 1) * 8;
    int gr = m0 + arow; if (gr >= M) gr = M - 1;
    float acc[8][8] = {};

    for (int kt = 0; kt < HDIM; kt += 16) {
        float f[8];
        *(float4*)&f[0] = *(const float4*)&A[(size_t)gr * HDIM + kt + acs];
        *(float4*)&f[4] = *(const float4*)&A[(size_t)gr * HDIM + kt + acs + 4];
#pragma unroll
        for (int j = 0; j < 8; j++) As[acs + j][arow] = f[j];
#pragma unroll
        for (int i = 0; i < 2; i++) {
            int lid = tid * 2 + i;
            int kr = lid >> 5, ns = (lid & 31) * 4;
            *(float4*)&Bs[kr][ns] =
                *(const float4*)&B[(size_t)(kt + kr) * HDIM + n0 + ns];
        }
        __syncthreads();
#pragma unroll
        for (int kl = 0; kl < 16; kl++) {
            float a[8], b[8];
            *(float4*)&a[0] = *(const float4*)&As[kl][ty * 8];
            *(float4*)&a[4] = *(const float4*)&As[kl][ty * 8 + 4];
            *(float4*)&b[0] = *(const float4*)&Bs[kl][tx * 8];
            *(float4*)&b[4] = *(const float4*)&Bs[kl][tx * 8 + 4];
#pragma unroll
            for (int i = 0; i < 8; i++)
#pragma unroll
                for (int j = 0; j < 8; j++)
                    acc[i][j] = fmaf(a[i], b[j], acc[i][j]);
        }
        __syncthreads();
    }

    float bv[8];
    *(float4*)&bv[0] = *(const float4*)&bias[n0 + tx * 8];
    *(float4*)&bv[4] = *(const float4*)&bias[n0 + tx * 8 + 4];
#pragma unroll
    for (int i = 0; i < 8; i++) {
        int gr2 = m0 + ty * 8 + i;
        if (gr2 >= M) break;
        float o[8];
#pragma unroll
        for (int j = 0; j < 8; j++) o[j] = acc[i][j] + bv[j];
        *(float4*)&C[(size_t)gr2 * HDIM + n0 + tx * 8]     = *(float4*)&o[0];
        *(float4*)&C[(size_t)gr2 * HDIM + n0 + tx * 8 + 4] = *(float4*)&o[4];
    }
}

// ================= pooling =================
__global__ __launch_bounds__(256) void bounds_kernel(
    const int* __restrict__ batch, int* __restrict__ gstart, int n, int ngraphs)
{
    int i = blockIdx.x * 256 + threadIdx.x;
    if (i >= n) return;
    int b1 = batch[i];
    int b0 = (i == 0) ? -1 : batch[i - 1];
    for (int g = b0 + 1; g <= b1; g++) gstart[g] = i;
    if (i == n - 1)
        for (int g = b1 + 1; g <= ngraphs; g++) gstart[g] = n;
}

__global__ __launch_bounds__(256) void pool_kernel(
    const unsigned short* __restrict__ h, const int* __restrict__ gstart,
    float* __restrict__ pooled, int ngraphs)
{
    int g = blockIdx.x * 4 + (threadIdx.x >> 6);
    if (g >= ngraphs) return;
    int lane = threadIdx.x & 63;
    int beg = gstart[g], end = gstart[g + 1];
    float a0 = 0.f, a1 = 0.f, a2 = 0.f, a3 = 0.f;
    for (int i = beg; i < end; i++) {
        uint2 r = *(const uint2*)&h[(size_t)i * HDIM + lane * 4];
        a0 += bflo(r.x); a1 += bfhi(r.x); a2 += bflo(r.y); a3 += bfhi(r.y);
    }
    float inv = 1.0f / fmaxf((float)(end - beg), 1.0f);
    float4 o = { a0 * inv, a1 * inv, a2 * inv, a3 * inv };
    *(float4*)&pooled[(size_t)g * HDIM + lane * 4] = o;
}

__global__ __launch_bounds__(256) void head2_kernel(
    const float* __restrict__ hh, const float* __restrict__ w2,
    const float* __restrict__ b2, float* __restrict__ out, int n_graphs)
{
    int g = blockIdx.x * 4 + (threadIdx.x >> 6);
    int lane = threadIdx.x & 63;
    float p = 0.f;
    if (g < n_graphs) {
        float4 v = *(const float4*)&hh[(size_t)g * HDIM + lane * 4];
        float4 w = *(const float4*)&w2[lane * 4];
        p = v.x * w.x + v.y * w.y + v.z * w.z + v.w * w.w;
    }
#pragma unroll
    for (int off = 32; off > 0; off >>= 1) p += __shfl_down(p, off, 64);
    if (g < n_graphs && lane == 0) out[g] = p + b2[0];
}

extern "C" void kernel_launch(void* const* d_in, const int* in_sizes, int n_in,
                              void* d_out, int out_size, void* d_ws, size_t ws_size,
                              hipStream_t stream)
{
    const float* x    = (const float*)d_in[0];
    const int*   ei   = (const int*)d_in[1];
    const int*   batch= (const int*)d_in[2];
    const float* g0w1 = (const float*)d_in[3];
    const float* g0b1 = (const float*)d_in[4];
    const float* g0w2 = (const float*)d_in[5];
    const float* g0b2 = (const float*)d_in[6];
    const float* gw1  = (const float*)d_in[7];
    const float* gb1  = (const float*)d_in[8];
    const float* gw2  = (const float*)d_in[9];
    const float* gb2  = (const float*)d_in[10];
    const float* hw1  = (const float*)d_in[11];
    const float* hb1  = (const float*)d_in[12];
    const float* hw2  = (const float*)d_in[13];
    const float* hb2  = (const float*)d_in[14];

    const int n_nodes  = in_sizes[0] / 11;
    const int n_edges  = in_sizes[1] / 2;
    const int n_graphs = out_size;

    const int* srcp = ei;
    const int* dstp = ei + n_edges;

    // ---- workspace carve-up (bytes) ----
    const size_t NF = (size_t)n_nodes * HDIM;
    char* p = (char*)d_ws;
    unsigned short* H0 = (unsigned short*)p; p += NF * 2;
    unsigned short* H1 = (unsigned short*)p; p += NF * 2;
    unsigned short* H2 = (unsigned short*)p; p += NF * 2;
    unsigned short* Bts = (unsigned short*)p; p += (size_t)9 * 65536 * 2;
    float* xsum    = (float*)p; p += (size_t)n_nodes * 11 * 4;
    float* pooled  = (float*)p; p += (size_t)n_graphs * HDIM * 4;
    float* hh      = (float*)p; p += (size_t)n_graphs * HDIM * 4;
    int* deg       = (int*)p; p += (size_t)n_nodes * 4;
    int* scanex    = (int*)p; p += (size_t)n_nodes * 4;
    int* partials  = (int*)p; p += 512 * 4;
    int* rowptr    = (int*)p; p += ((size_t)n_nodes + 1) * 4;
    int* cursor    = (int*)p; p += (size_t)n_nodes * 4;
    int* csr_src   = (int*)p; p += (size_t)n_edges * 4;
    int* gstart    = (int*)p; p += ((size_t)n_graphs + 1) * 4;
    if ((size_t)(p - (char*)d_ws) > ws_size) return;

    const int nblk = (n_nodes + 255) / 256;

    // ---- weight convert (independent of CSR) ----
    convw_kernel<<<(9 * 65536 + 255) / 256, 256, 0, stream>>>(g0w2, gw1, gw2, Bts);

    // ---- CSR build ----
    hipMemsetAsync(deg, 0, (size_t)n_nodes * 4, stream);
    hist_kernel<<<(n_edges + 255) / 256, 256, 0, stream>>>(dstp, deg, n_edges);
    scan1_kernel<<<nblk, 256, 0, stream>>>(deg, scanex, partials, n_nodes);
    scan2_kernel<<<1, 512, 0, stream>>>(partials, nblk);
    scan3_kernel<<<nblk, 256, 0, stream>>>(scanex, partials, rowptr, cursor,
                                           n_nodes, n_edges);
    fill_kernel<<<(n_edges + 255) / 256, 256, 0, stream>>>(
        srcp, dstp, cursor, csr_src, n_edges);

    bounds_kernel<<<nblk, 256, 0, stream>>>(batch, gstart, n_nodes, n_graphs);

    const int gemmGridX = (n_nodes + 127) / 128;
    const int aggGrid   = (n_nodes + 3) / 4;

    // ---- gin0 (IN=11) ----
    agg0_kernel<<<((size_t)n_nodes * 16 + 255) / 256, 256, 0, stream>>>(
        x, rowptr, csr_src, xsum, n_nodes);
    gemm0_kernel<<<aggGrid, 256, 0, stream>>>(xsum, g0w1, g0b1, H1, n_nodes);
    gemm_mfma<<<dim3(gemmGridX, 2), 256, 0, stream>>>(
        H1, Bts + 0, g0b2, H0, n_nodes, 1);

    // ---- 4 GIN layers ----
    unsigned short* cur = H0;
    unsigned short* t   = H1;
    unsigned short* y   = H2;
    for (int l = 0; l < 4; l++) {
        const float* b1 = gb1 + (size_t)l * HDIM;
        const float* b2 = gb2 + (size_t)l * HDIM;
        agg_bf_kernel<<<aggGrid, 256, 0, stream>>>(cur, rowptr, csr_src, t, n_nodes);
        gemm_mfma<<<dim3(gemmGridX, 2), 256, 0, stream>>>(
            t, Bts + (size_t)(1 + l) * 65536, b1, y, n_nodes, 1);
        gemm_mfma<<<dim3(gemmGridX, 2), 256, 0, stream>>>(
            y, Bts + (size_t)(5 + l) * 65536, b2, t, n_nodes, 1);
        unsigned short* dead = cur;
        cur = t; t = dead;
    }

    // ---- mean pool ----
    pool_kernel<<<(n_graphs + 3) / 4, 256, 0, stream>>>(cur, gstart, pooled, n_graphs);

    // ---- head ----
    gemm_head<<<dim3((n_graphs + 127) / 128, 2), 256, 0, stream>>>(
        pooled, hw1, hb1, hh, n_graphs);
    head2_kernel<<<(n_graphs + 3) / 4, 256, 0, stream>>>(
        hh, hw2, hb2, (float*)d_out, n_graphs);
}

// Round 5
// 665.246 us; speedup vs baseline: 11.2540x; 1.1869x over previous
//
#include <hip/hip_runtime.h>
#include <hip/hip_bf16.h>

// GIN forward, round 5: fused MLP kernel (both 256x256 GEMMs of a GIN layer
// in one kernel, Y parked in LDS) + 16B-load half-wave aggregation.

constexpr int HDIM = 256;

typedef short v8s __attribute__((ext_vector_type(8)));
typedef float v4f __attribute__((ext_vector_type(4)));

__device__ __forceinline__ float bflo(unsigned int u) { return __uint_as_float(u << 16); }
__device__ __forceinline__ float bfhi(unsigned int u) { return __uint_as_float(u & 0xffff0000u); }
__device__ __forceinline__ unsigned short f2bf(float f) {
    unsigned int u = __float_as_uint(f);
    return (unsigned short)((u + 0x7fffu + ((u >> 16) & 1u)) >> 16);  // RNE
}

__device__ __forceinline__ void gload16(const void* g, void* l) {
    __builtin_amdgcn_global_load_lds(
        (const __attribute__((address_space(1))) unsigned int*)g,
        (__attribute__((address_space(3))) unsigned int*)l, 16, 0, 0);
}

// ================= CSR build =================
__global__ __launch_bounds__(256) void hist_kernel(
    const int* __restrict__ dst, int* __restrict__ deg, int n_edges)
{
    int e = blockIdx.x * 256 + threadIdx.x;
    if (e < n_edges) atomicAdd(&deg[dst[e]], 1);
}

__global__ __launch_bounds__(256) void scan1_kernel(
    const int* __restrict__ deg, int* __restrict__ scanex,
    int* __restrict__ partials, int n)
{
    __shared__ int s[256];
    int i = blockIdx.x * 256 + threadIdx.x;
    int v = (i < n) ? deg[i] : 0;
    s[threadIdx.x] = v;
    __syncthreads();
#pragma unroll
    for (int off = 1; off < 256; off <<= 1) {
        int t = (threadIdx.x >= off) ? s[threadIdx.x - off] : 0;
        __syncthreads();
        s[threadIdx.x] += t;
        __syncthreads();
    }
    if (i < n) scanex[i] = s[threadIdx.x] - v;
    if (threadIdx.x == 255) partials[blockIdx.x] = s[255];
}

__global__ __launch_bounds__(512) void scan2_kernel(int* __restrict__ partials, int nb)
{
    __shared__ int s[512];
    int v = (threadIdx.x < nb) ? partials[threadIdx.x] : 0;
    s[threadIdx.x] = v;
    __syncthreads();
#pragma unroll
    for (int off = 1; off < 512; off <<= 1) {
        int t = (threadIdx.x >= off) ? s[threadIdx.x - off] : 0;
        __syncthreads();
        s[threadIdx.x] += t;
        __syncthreads();
    }
    if (threadIdx.x < nb) partials[threadIdx.x] = s[threadIdx.x] - v;
}

__global__ __launch_bounds__(256) void scan3_kernel(
    const int* __restrict__ scanex, const int* __restrict__ partials,
    int* __restrict__ rowptr, int* __restrict__ cursor, int n, int n_edges)
{
    int i = blockIdx.x * 256 + threadIdx.x;
    if (i < n) {
        int v = scanex[i] + partials[blockIdx.x];
        rowptr[i] = v;
        cursor[i] = v;
    }
    if (i == 0) rowptr[n] = n_edges;
}

__global__ __launch_bounds__(256) void fill_kernel(
    const int* __restrict__ src, const int* __restrict__ dst,
    int* __restrict__ cursor, int* __restrict__ csr_src, int n_edges)
{
    int e = blockIdx.x * 256 + threadIdx.x;
    if (e >= n_edges) return;
    int slot = atomicAdd(&cursor[dst[e]], 1);
    csr_src[slot] = src[e];
}

// ================= weight convert: Wt[n][k] = bf16(W[k][n]) =================
__global__ __launch_bounds__(256) void convw_kernel(
    const float* __restrict__ g0w2, const float* __restrict__ gw1,
    const float* __restrict__ gw2, unsigned short* __restrict__ Bts)
{
    int gid = blockIdx.x * 256 + threadIdx.x;
    if (gid >= 9 * 65536) return;
    int m = gid >> 16;
    int e = gid & 0xffff;
    int n = e >> 8, k = e & 255;
    const float* W = (m == 0) ? g0w2
                   : (m <= 4) ? gw1 + (size_t)(m - 1) * 65536
                              : gw2 + (size_t)(m - 5) * 65536;
    Bts[(size_t)m * 65536 + n * 256 + k] = f2bf(W[k * 256 + n]);
}

// ================= aggregation (gather) =================
__global__ __launch_bounds__(256) void agg0_kernel(
    const float* __restrict__ x, const int* __restrict__ rowptr,
    const int* __restrict__ csr_src, float* __restrict__ xsum, int n)
{
    int gid = blockIdx.x * 256 + threadIdx.x;
    int node = gid >> 4, f = gid & 15;
    if (node >= n || f >= 11) return;
    float acc = x[(size_t)node * 11 + f];
    int beg = rowptr[node], end = rowptr[node + 1];
    for (int e = beg; e < end; e++)
        acc += x[(size_t)csr_src[e] * 11 + f];
    xsum[(size_t)node * 11 + f] = acc;
}

// half-wave (32 lanes x 16B) per node
__global__ __launch_bounds__(256) void agg_bf_kernel(
    const unsigned short* __restrict__ h, const int* __restrict__ rowptr,
    const int* __restrict__ csr_src, unsigned short* __restrict__ out, int n)
{
    int node = blockIdx.x * 8 + (threadIdx.x >> 5);
    if (node >= n) return;
    int l = threadIdx.x & 31;
    uint4 raw = *(const uint4*)&h[(size_t)node * HDIM + l * 8];
    float a0 = bflo(raw.x), a1 = bfhi(raw.x), a2 = bflo(raw.y), a3 = bfhi(raw.y);
    float a4 = bflo(raw.z), a5 = bfhi(raw.z), a6 = bflo(raw.w), a7 = bfhi(raw.w);
    int beg = rowptr[node], end = rowptr[node + 1];
    for (int e = beg; e < end; e++) {
        int s = csr_src[e];
        uint4 r = *(const uint4*)&h[(size_t)s * HDIM + l * 8];
        a0 += bflo(r.x); a1 += bfhi(r.x); a2 += bflo(r.y); a3 += bfhi(r.y);
        a4 += bflo(r.z); a5 += bfhi(r.z); a6 += bflo(r.w); a7 += bfhi(r.w);
    }
    uint4 o;
    o.x = (unsigned int)f2bf(a0) | ((unsigned int)f2bf(a1) << 16);
    o.y = (unsigned int)f2bf(a2) | ((unsigned int)f2bf(a3) << 16);
    o.z = (unsigned int)f2bf(a4) | ((unsigned int)f2bf(a5) << 16);
    o.w = (unsigned int)f2bf(a6) | ((unsigned int)f2bf(a7) << 16);
    *(uint4*)&out[(size_t)node * HDIM + l * 8] = o;
}

// ================= layer-0 GEMM (K=11) =================
__global__ __launch_bounds__(256) void gemm0_kernel(
    const float* __restrict__ xsum, const float* __restrict__ w1,
    const float* __restrict__ b1, unsigned short* __restrict__ out, int M)
{
    int row = blockIdx.x * 4 + (threadIdx.x >> 6);
    if (row >= M) return;
    int lane = threadIdx.x & 63;
    float xr[11];
#pragma unroll
    for (int k = 0; k < 11; k++) xr[k] = xsum[(size_t)row * 11 + k];
    int n = lane * 4;
    float4 acc = *(const float4*)&b1[n];
#pragma unroll
    for (int k = 0; k < 11; k++) {
        float4 w = *(const float4*)&w1[k * HDIM + n];
        acc.x = fmaf(xr[k], w.x, acc.x);
        acc.y = fmaf(xr[k], w.y, acc.y);
        acc.z = fmaf(xr[k], w.z, acc.z);
        acc.w = fmaf(xr[k], w.w, acc.w);
    }
    uint2 o;
    o.x = (unsigned int)f2bf(fmaxf(acc.x, 0.f)) | ((unsigned int)f2bf(fmaxf(acc.y, 0.f)) << 16);
    o.y = (unsigned int)f2bf(fmaxf(acc.z, 0.f)) | ((unsigned int)f2bf(fmaxf(acc.w, 0.f)) << 16);
    *(uint2*)&out[(size_t)row * HDIM + n] = o;
}

// ================= single MFMA GEMM (layer-0 second linear) =================
__global__ __launch_bounds__(256) void gemm_mfma(
    const unsigned short* __restrict__ A, const unsigned short* __restrict__ Wt,
    const float* __restrict__ bias, unsigned short* __restrict__ C,
    int M, int do_relu)
{
    __shared__ short lds[2][512 * 8];
    const int tid = threadIdx.x;
    const int w = tid >> 6, lane = tid & 63;
    const int q = lane >> 4, r = lane & 15;
    const int rh = w & 1, ch = w >> 1;
    const int m0 = blockIdx.x * 128, n0 = blockIdx.y * 128;

    v4f acc[4][4];
#pragma unroll
    for (int i = 0; i < 4; i++)
#pragma unroll
        for (int j = 0; j < 4; j++)
            acc[i][j] = (v4f){0.f, 0.f, 0.f, 0.f};

    for (int kt = 0; kt < HDIM; kt += 32) {
#pragma unroll
        for (int rd = 0; rd < 2; rd++) {
            int cb = rd * 256 + w * 64;
            int s  = cb + lane;
            int row = s >> 2;
            int ko  = ((s & 3) - (row >> 1)) & 3;
            int gr = m0 + row; if (gr >= M) gr = M - 1;
            gload16(&A[(size_t)gr * HDIM + kt + ko * 8],  &lds[0][cb * 8]);
            gload16(&Wt[(size_t)(n0 + row) * HDIM + kt + ko * 8], &lds[1][cb * 8]);
        }
        __syncthreads();
        v8s af[4], bf[4];
#pragma unroll
        for (int mi = 0; mi < 4; mi++) {
            int row = rh * 64 + mi * 16 + r;
            int slot = row * 4 + ((q + (row >> 1)) & 3);
            af[mi] = *(const v8s*)&lds[0][slot * 8];
        }
#pragma unroll
        for (int ni = 0; ni < 4; ni++) {
            int row = ch * 64 + ni * 16 + r;
            int slot = row * 4 + ((q + (row >> 1)) & 3);
            bf[ni] = *(const v8s*)&lds[1][slot * 8];
        }
#pragma unroll
        for (int mi = 0; mi < 4; mi++)
#pragma unroll
            for (int ni = 0; ni < 4; ni++)
                acc[mi][ni] = __builtin_amdgcn_mfma_f32_16x16x32_bf16(
                    af[mi], bf[ni], acc[mi][ni], 0, 0, 0);
        __syncthreads();
    }

    float bv[4];
#pragma unroll
    for (int ni = 0; ni < 4; ni++)
        bv[ni] = bias[n0 + ch * 64 + ni * 16 + r];

    short* cw = &lds[0][0] + w * (16 * 72);
#pragma unroll
    for (int mi = 0; mi < 4; mi++) {
#pragma unroll
        for (int ni = 0; ni < 4; ni++)
#pragma unroll
            for (int i = 0; i < 4; i++) {
                float v = acc[mi][ni][i] + bv[ni];
                if (do_relu) v = fmaxf(v, 0.f);
                cw[(q * 4 + i) * 72 + ni * 16 + r] = (short)f2bf(v);
            }
        __syncthreads();
        int row = lane >> 2, seg = lane & 3;
        int gm = m0 + rh * 64 + mi * 16 + row;
        if (gm < M) {
            v8s p0 = *(const v8s*)&cw[row * 72 + seg * 16];
            v8s p1 = *(const v8s*)&cw[row * 72 + seg * 16 + 8];
            size_t o = (size_t)gm * HDIM + n0 + ch * 64 + seg * 16;
            *(v8s*)&C[o]     = p0;
            *(v8s*)&C[o + 8] = p1;
        }
        __syncthreads();
    }
}

// ================= fused GIN MLP: C = relu(relu(A@W1+b1)@W2+b2) =============
// 64-row block, 256 threads (4 waves). Wave w computes cols [w*64, w*64+64)
// of both GEMMs. Y (64x256 bf16) parked in LDS in swizzled chunk-slot format
// so phase-2 A-frags are plain ds_read_b128. In-place C==A is safe.
__global__ __launch_bounds__(256) void mlp_fused(
    const unsigned short* __restrict__ A,
    const unsigned short* __restrict__ W1t, const float* __restrict__ b1,
    const unsigned short* __restrict__ W2t, const float* __restrict__ b2,
    unsigned short* __restrict__ C, int M)
{
    __shared__ short Ybuf[8 * 2048];    // 32 KB: 8 chunks x 256 slots x 16B
    __shared__ short Astage[256 * 8];   // 4 KB
    __shared__ short Wstage[1024 * 8];  // 16 KB
    const int tid = threadIdx.x;
    const int w = tid >> 6, lane = tid & 63;
    const int q = lane >> 4, r = lane & 15;
    const int m0 = blockIdx.x * 64;

    v4f acc[4][4];
#pragma unroll
    for (int i = 0; i < 4; i++)
#pragma unroll
        for (int j = 0; j < 4; j++)
            acc[i][j] = (v4f){0.f, 0.f, 0.f, 0.f};

    // ---- phase 1: Y = relu(A @ W1 + b1) ----
    for (int kc = 0; kc < 8; kc++) {
        int kt = kc * 32;
        {   // A chunk: 256 slots, one gload16 per thread
            int s = tid;
            int row = s >> 2;
            int ko = ((s & 3) - (row >> 1)) & 3;
            int gr = m0 + row; if (gr >= M) gr = M - 1;
            gload16(&A[(size_t)gr * HDIM + kt + ko * 8], &Astage[(w * 64) * 8]);
        }
#pragma unroll
        for (int rd = 0; rd < 4; rd++) {  // W1t chunk: 1024 slots
            int cb = rd * 256 + w * 64;
            int s = cb + lane;
            int n = s >> 2;
            int ko = ((s & 3) - (n >> 1)) & 3;
            gload16(&W1t[(size_t)n * HDIM + kt + ko * 8], &Wstage[cb * 8]);
        }
        __syncthreads();
        v8s af[4], bf[4];
#pragma unroll
        for (int mi = 0; mi < 4; mi++) {
            int row = mi * 16 + r;
            int slot = row * 4 + ((q + (row >> 1)) & 3);
            af[mi] = *(const v8s*)&Astage[slot * 8];
        }
#pragma unroll
        for (int ni = 0; ni < 4; ni++) {
            int n = w * 64 + ni * 16 + r;
            int slot = n * 4 + ((q + (n >> 1)) & 3);
            bf[ni] = *(const v8s*)&Wstage[slot * 8];
        }
#pragma unroll
        for (int mi = 0; mi < 4; mi++)
#pragma unroll
            for (int ni = 0; ni < 4; ni++)
                acc[mi][ni] = __builtin_amdgcn_mfma_f32_16x16x32_bf16(
                    af[mi], bf[ni], acc[mi][ni], 0, 0, 0);
        __syncthreads();
    }

    // Y -> LDS (bias + relu), swizzled chunk-slot layout
    {
        float bv1[4];
#pragma unroll
        for (int ni = 0; ni < 4; ni++)
            bv1[ni] = b1[w * 64 + ni * 16 + r];
#pragma unroll
        for (int mi = 0; mi < 4; mi++)
#pragma unroll
            for (int ni = 0; ni < 4; ni++)
#pragma unroll
                for (int i = 0; i < 4; i++) {
                    float v = fmaxf(acc[mi][ni][i] + bv1[ni], 0.f);
                    int row = mi * 16 + q * 4 + i;
                    int col = w * 64 + ni * 16 + r;
                    int chunk = col >> 5, kk = col & 31;
                    int ko = kk >> 3, j = kk & 7;
                    int slot = row * 4 + ((ko + (row >> 1)) & 3);
                    Ybuf[chunk * 2048 + slot * 8 + j] = (short)f2bf(v);
                }
    }
    __syncthreads();

    // ---- phase 2: C = relu(Y @ W2 + b2) ----
    v4f acc2[4][4];
#pragma unroll
    for (int i = 0; i < 4; i++)
#pragma unroll
        for (int j = 0; j < 4; j++)
            acc2[i][j] = (v4f){0.f, 0.f, 0.f, 0.f};

    for (int kc = 0; kc < 8; kc++) {
        int kt = kc * 32;
#pragma unroll
        for (int rd = 0; rd < 4; rd++) {
            int cb = rd * 256 + w * 64;
            int s = cb + lane;
            int n = s >> 2;
            int ko = ((s & 3) - (n >> 1)) & 3;
            gload16(&W2t[(size_t)n * HDIM + kt + ko * 8], &Wstage[cb * 8]);
        }
        __syncthreads();
        v8s af[4], bf[4];
#pragma unroll
        for (int mi = 0; mi < 4; mi++) {
            int row = mi * 16 + r;
            int slot = row * 4 + ((q + (row >> 1)) & 3);
            af[mi] = *(const v8s*)&Ybuf[kc * 2048 + slot * 8];
        }
#pragma unroll
        for (int ni = 0; ni < 4; ni++) {
            int n = w * 64 + ni * 16 + r;
            int slot = n * 4 + ((q + (n >> 1)) & 3);
            bf[ni] = *(const v8s*)&Wstage[slot * 8];
        }
#pragma unroll
        for (int mi = 0; mi < 4; mi++)
#pragma unroll
            for (int ni = 0; ni < 4; ni++)
                acc2[mi][ni] = __builtin_amdgcn_mfma_f32_16x16x32_bf16(
                    af[mi], bf[ni], acc2[mi][ni], 0, 0, 0);
        __syncthreads();
    }

    // epilogue: bias2 + relu, LDS bounce (reuse Ybuf), coalesced stores
    float bv2[4];
#pragma unroll
    for (int ni = 0; ni < 4; ni++)
        bv2[ni] = b2[w * 64 + ni * 16 + r];
    short* cw = &Ybuf[w * 1152];   // 16 rows x 72 stride
#pragma unroll
    for (int mi = 0; mi < 4; mi++) {
#pragma unroll
        for (int ni = 0; ni < 4; ni++)
#pragma unroll
            for (int i = 0; i < 4; i++) {
                float v = fmaxf(acc2[mi][ni][i] + bv2[ni], 0.f);
                cw[(q * 4 + i) * 72 + ni * 16 + r] = (short)f2bf(v);
            }
        __syncthreads();
        int row = lane >> 2, seg = lane & 3;
        int gm = m0 + mi * 16 + row;
        if (gm < M) {
            v8s p0 = *(const v8s*)&cw[row * 72 + seg * 16];
            v8s p1 = *(const v8s*)&cw[row * 72 + seg * 16 + 8];
            size_t o = (size_t)gm * HDIM + w * 64 + seg * 16;
            *(v8s*)&C[o]     = p0;
            *(v8s*)&C[o + 8] = p1;
        }
        __syncthreads();
    }
}

// ================= head GEMM (fp32, M=5000) =================
__global__ __launch_bounds__(256) void gemm_head(
    const float* __restrict__ A, const float* __restrict__ B,
    const float* __restrict__ bias, float* __restrict__ C, int M)
{
    __shared__ float As[16][132];
    __shared__ float Bs[16][132];
    const int tid = threadIdx.x;
    const int tx = tid & 15, ty = tid >> 4;
    const int m0 = blockIdx.x * 128, n0 = blockIdx.y * 128;
    const int arow = tid >> 1, acs = (tid & 1) * 8;
    int gr = m0 + arow; if (gr >= M) gr = M - 1;
    float acc[8][8] = {};

    for (int kt = 0; kt < HDIM; kt += 16) {
        float f[8];
        *(float4*)&f[0] = *(const float4*)&A[(size_t)gr * HDIM + kt + acs];
        *(float4*)&f[4] = *(const float4*)&A[(size_t)gr * HDIM + kt + acs + 4];
#pragma unroll
        for (int j = 0; j < 8; j++) As[acs + j][arow] = f[j];
#pragma unroll
        for (int i = 0; i < 2; i++) {
            int lid = tid * 2 + i;
            int kr = lid >> 5, ns = (lid & 31) * 4;
            *(float4*)&Bs[kr][ns] =
                *(const float4*)&B[(size_t)(kt + kr) * HDIM + n0 + ns];
        }
        __syncthreads();
#pragma unroll
        for (int kl = 0; kl < 16; kl++) {
            float a[8], b[8];
            *(float4*)&a[0] = *(const float4*)&As[kl][ty * 8];
            *(float4*)&a[4] = *(const float4*)&As[kl][ty * 8 + 4];
            *(float4*)&b[0] = *(const float4*)&Bs[kl][tx * 8];
            *(float4*)&b[4] = *(const float4*)&Bs[kl][tx * 8 + 4];
#pragma unroll
            for (int i = 0; i < 8; i++)
#pragma unroll
                for (int j = 0; j < 8; j++)
                    acc[i][j] = fmaf(a[i], b[j], acc[i][j]);
        }
        __syncthreads();
    }

    float bv[8];
    *(float4*)&bv[0] = *(const float4*)&bias[n0 + tx * 8];
    *(float4*)&bv[4] = *(const float4*)&bias[n0 + tx * 8 + 4];
#pragma unroll
    for (int i = 0; i < 8; i++) {
        int gr2 = m0 + ty * 8 + i;
        if (gr2 >= M) break;
        float o[8];
#pragma unroll
        for (int j = 0; j < 8; j++) o[j] = acc[i][j] + bv[j];
        *(float4*)&C[(size_t)gr2 * HDIM + n0 + tx * 8]     = *(float4*)&o[0];
        *(float4*)&C[(size_t)gr2 * HDIM + n0 + tx * 8 + 4] = *(float4*)&o[4];
    }
}

// ================= pooling =================
__global__ __launch_bounds__(256) void bounds_kernel(
    const int* __restrict__ batch, int* __restrict__ gstart, int n, int ngraphs)
{
    int i = blockIdx.x * 256 + threadIdx.x;
    if (i >= n) return;
    int b1 = batch[i];
    int b0 = (i == 0) ? -1 : batch[i - 1];
    for (int g = b0 + 1; g <= b1; g++) gstart[g] = i;
    if (i == n - 1)
        for (int g = b1 + 1; g <= ngraphs; g++) gstart[g] = n;
}

__global__ __launch_bounds__(256) void pool_kernel(
    const unsigned short* __restrict__ h, const int* __restrict__ gstart,
    float* __restrict__ pooled, int ngraphs)
{
    int g = blockIdx.x * 4 + (threadIdx.x >> 6);
    if (g >= ngraphs) return;
    int lane = threadIdx.x & 63;
    int beg = gstart[g], end = gstart[g + 1];
    float a0 = 0.f, a1 = 0.f, a2 = 0.f, a3 = 0.f;
    for (int i = beg; i < end; i++) {
        uint2 r = *(const uint2*)&h[(size_t)i * HDIM + lane * 4];
        a0 += bflo(r.x); a1 += bfhi(r.x); a2 += bflo(r.y); a3 += bfhi(r.y);
    }
    float inv = 1.0f / fmaxf((float)(end - beg), 1.0f);
    float4 o = { a0 * inv, a1 * inv, a2 * inv, a3 * inv };
    *(float4*)&pooled[(size_t)g * HDIM + lane * 4] = o;
}

__global__ __launch_bounds__(256) void head2_kernel(
    const float* __restrict__ hh, const float* __restrict__ w2,
    const float* __restrict__ b2, float* __restrict__ out, int n_graphs)
{
    int g = blockIdx.x * 4 + (threadIdx.x >> 6);
    int lane = threadIdx.x & 63;
    float p = 0.f;
    if (g < n_graphs) {
        float4 v = *(const float4*)&hh[(size_t)g * HDIM + lane * 4];
        float4 w = *(const float4*)&w2[lane * 4];
        p = v.x * w.x + v.y * w.y + v.z * w.z + v.w * w.w;
    }
#pragma unroll
    for (int off = 32; off > 0; off >>= 1) p += __shfl_down(p, off, 64);
    if (g < n_graphs && lane == 0) out[g] = p + b2[0];
}

extern "C" void kernel_launch(void* const* d_in, const int* in_sizes, int n_in,
                              void* d_out, int out_size, void* d_ws, size_t ws_size,
                              hipStream_t stream)
{
    const float* x    = (const float*)d_in[0];
    const int*   ei   = (const int*)d_in[1];
    const int*   batch= (const int*)d_in[2];
    const float* g0w1 = (const float*)d_in[3];
    const float* g0b1 = (const float*)d_in[4];
    const float* g0w2 = (const float*)d_in[5];
    const float* g0b2 = (const float*)d_in[6];
    const float* gw1  = (const float*)d_in[7];
    const float* gb1  = (const float*)d_in[8];
    const float* gw2  = (const float*)d_in[9];
    const float* gb2  = (const float*)d_in[10];
    const float* hw1  = (const float*)d_in[11];
    const float* hb1  = (const float*)d_in[12];
    const float* hw2  = (const float*)d_in[13];
    const float* hb2  = (const float*)d_in[14];

    const int n_nodes  = in_sizes[0] / 11;
    const int n_edges  = in_sizes[1] / 2;
    const int n_graphs = out_size;

    const int* srcp = ei;
    const int* dstp = ei + n_edges;

    // ---- workspace carve-up (bytes) ----
    const size_t NF = (size_t)n_nodes * HDIM;
    char* p = (char*)d_ws;
    unsigned short* H0 = (unsigned short*)p; p += NF * 2;
    unsigned short* H1 = (unsigned short*)p; p += NF * 2;
    unsigned short* Bts = (unsigned short*)p; p += (size_t)9 * 65536 * 2;
    float* xsum    = (float*)p; p += (size_t)n_nodes * 11 * 4;
    float* pooled  = (float*)p; p += (size_t)n_graphs * HDIM * 4;
    float* hh      = (float*)p; p += (size_t)n_graphs * HDIM * 4;
    int* deg       = (int*)p; p += (size_t)n_nodes * 4;
    int* scanex    = (int*)p; p += (size_t)n_nodes * 4;
    int* partials  = (int*)p; p += 512 * 4;
    int* rowptr    = (int*)p; p += ((size_t)n_nodes + 1) * 4;
    int* cursor    = (int*)p; p += (size_t)n_nodes * 4;
    int* csr_src   = (int*)p; p += (size_t)n_edges * 4;
    int* gstart    = (int*)p; p += ((size_t)n_graphs + 1) * 4;
    if ((size_t)(p - (char*)d_ws) > ws_size) return;

    const int nblk = (n_nodes + 255) / 256;

    // ---- weight convert ----
    convw_kernel<<<(9 * 65536 + 255) / 256, 256, 0, stream>>>(g0w2, gw1, gw2, Bts);

    // ---- CSR build ----
    hipMemsetAsync(deg, 0, (size_t)n_nodes * 4, stream);
    hist_kernel<<<(n_edges + 255) / 256, 256, 0, stream>>>(dstp, deg, n_edges);
    scan1_kernel<<<nblk, 256, 0, stream>>>(deg, scanex, partials, n_nodes);
    scan2_kernel<<<1, 512, 0, stream>>>(partials, nblk);
    scan3_kernel<<<nblk, 256, 0, stream>>>(scanex, partials, rowptr, cursor,
                                           n_nodes, n_edges);
    fill_kernel<<<(n_edges + 255) / 256, 256, 0, stream>>>(
        srcp, dstp, cursor, csr_src, n_edges);

    bounds_kernel<<<nblk, 256, 0, stream>>>(batch, gstart, n_nodes, n_graphs);

    // ---- gin0 (IN=11) ----
    agg0_kernel<<<((size_t)n_nodes * 16 + 255) / 256, 256, 0, stream>>>(
        x, rowptr, csr_src, xsum, n_nodes);
    gemm0_kernel<<<(n_nodes + 3) / 4, 256, 0, stream>>>(xsum, g0w1, g0b1, H1, n_nodes);
    gemm_mfma<<<dim3((n_nodes + 127) / 128, 2), 256, 0, stream>>>(
        H1, Bts + 0, g0b2, H0, n_nodes, 1);

    // ---- 4 GIN layers: agg(cur->t), fused MLP(t)->cur ----
    unsigned short* cur = H0;
    unsigned short* t   = H1;
    const int aggGrid = (n_nodes + 7) / 8;
    const int mlpGrid = (n_nodes + 63) / 64;
    for (int l = 0; l < 4; l++) {
        agg_bf_kernel<<<aggGrid, 256, 0, stream>>>(cur, rowptr, csr_src, t, n_nodes);
        mlp_fused<<<mlpGrid, 256, 0, stream>>>(
            t, Bts + (size_t)(1 + l) * 65536, gb1 + (size_t)l * HDIM,
            Bts + (size_t)(5 + l) * 65536, gb2 + (size_t)l * HDIM,
            cur, n_nodes);
    }

    // ---- mean pool ----
    pool_kernel<<<(n_graphs + 3) / 4, 256, 0, stream>>>(cur, gstart, pooled, n_graphs);

    // ---- head ----
    gemm_head<<<dim3((n_graphs + 127) / 128, 2), 256, 0, stream>>>(
        pooled, hw1, hb1, hh, n_graphs);
    head2_kernel<<<(n_graphs + 3) / 4, 256, 0, stream>>>(
        hh, hw2, hb2, (float*)d_out, n_graphs);
}